// Round 9
// baseline (173.027 us; speedup 1.0000x reference)
//
#include <hip/hip_runtime.h>
#include <stdint.h>

#define TPB 256
#define BB  128
#define SS  512
#define LLW 20
#define NN  (BB * SS * LLW)   // 1,310,720
#define FPT 8                 // f's (or k's) per thread in K1/K2
#define KPB3 1024             // k-rows per block in K3
#define MAXROWS 8             // staged seqs rows (proven bound: 6)
#define RSTRIDE 516           // LDS row stride (ints), 16B-aligned

// lens -> LDS; inclusive prefix of per-batch viable counts
// (count(b) = L*len_b - L(L-1)/2, len>=L guaranteed) and max(lens).
static __device__ __forceinline__ void preamble(const int* __restrict__ lens,
                                                int* shC, int* shM, int* shLen,
                                                int t) {
  int len0 = (t < BB) ? lens[t] : 0;
  shLen[t] = len0;
  shC[t] = (t < BB) ? (LLW * len0 - (LLW * (LLW - 1)) / 2) : 0;
  shM[t] = len0;
  for (int off = 1; off < TPB; off <<= 1) {
    __syncthreads();
    int aC = shC[t]; int bC = (t >= off) ? shC[t - off] : 0;
    int aM = shM[t]; int bM = shM[t ^ off];
    __syncthreads();
    shC[t] = aC + bC;
    shM[t] = (aM > bM) ? aM : bM;
  }
  __syncthreads();
}

static __device__ __forceinline__ int batch_of(int k, const int* shC) {
  int lo = 0, hi = BB - 1;
  while (lo < hi) {
    int mid = (lo + hi) >> 1;
    if (shC[mid] > k) hi = mid; else lo = mid + 1;
  }
  return lo;
}

static __device__ __forceinline__ void invert(int k, const int* shC,
                                              const int* shLen, int K,
                                              int* pb, int* ps, int* pj) {
  int b = 0, s = 0, j = 0;
  if (k < K) {
    b = batch_of(k, shC);
    int base = (b == 0) ? 0 : shC[b - 1];
    int m    = k - base;
    int lenb = shLen[b];
    int full = LLW * (lenb - LLW + 1);
    if (m < full) {
      s = m / LLW;
      j = m - s * LLW;
    } else {                             // triangular tail; r = lenb - s
      int Cb = shC[b] - base;
      int tt = Cb - m;
      float rf = (sqrtf(8.0f * (float)tt + 1.0f) - 1.0f) * 0.5f;
      int r = (int)(rf + 0.5f);
      if (r * (r + 1) / 2 < tt) r++;
      if (r > 1 && r * (r - 1) / 2 >= tt) r--;
      s = lenb - r;
      j = r * (r + 1) / 2 - tt;
    }
  }
  *pb = b; *ps = s; *pj = j;
}

// ---------------- K1: candidate regions 0, 26, 27, 28 (84 MB) ----------------
__global__ __launch_bounds__(TPB) void k_cand(const int* __restrict__ lens,
                                              float* __restrict__ out) {
  __shared__ int shLen[BB];
  const int t = threadIdx.x;
  if (t < BB) shLen[t] = lens[t];
  __syncthreads();
  const size_t Nz = (size_t)NN;
  const int f0 = (blockIdx.x * TPB + t) * FPT;
  float qv[FPT], qsc[FPT], qec[FPT], qlc[FPT];
#pragma unroll
  for (int i = 0; i < FPT; i++) {
    int f   = f0 + i;
    int row = f / LLW;
    int jj  = f - row * LLW;
    int b   = row >> 9;
    int s   = row & (SS - 1);
    int e   = s + jj;
    qv[i]  = (e < shLen[b]) ? 1.0f : 0.0f;
    qsc[i] = (float)s; qec[i] = (float)e; qlc[i] = (float)(jj + 1);
  }
#pragma unroll
  for (int h = 0; h < FPT / 4; h++) {
    int o = 4 * h;
    *(float4*)(out + f0 + o)           = make_float4(qv[o], qv[o+1], qv[o+2], qv[o+3]);
    *(float4*)(out + 26 * Nz + f0 + o) = make_float4(qsc[o], qsc[o+1], qsc[o+2], qsc[o+3]);
    *(float4*)(out + 27 * Nz + f0 + o) = make_float4(qec[o], qec[o+1], qec[o+2], qec[o+3]);
    *(float4*)(out + 28 * Nz + f0 + o) = make_float4(qlc[o], qlc[o+1], qlc[o+2], qlc[o+3]);
  }
}

// ------- K2: compacted scalar regions 1,2,3,4,25 (26 MB) + (b,s) table -------
__global__ __launch_bounds__(TPB) void k_scal(const int* __restrict__ lens,
                                              const float* __restrict__ pw,
                                              float* __restrict__ out,
                                              int* __restrict__ wsbs) {
  __shared__ int shC[TPB], shM[TPB], shLen[TPB];
  const int t = threadIdx.x;
  preamble(lens, shC, shM, shLen, t);
  const int K = shC[BB - 1];
  const size_t Nz = (size_t)NN;
  const int k0 = (blockIdx.x * TPB + t) * FPT;

  int b, s, j;
  invert(k0, shC, shLen, K, &b, &s, &j);
  float qb[FPT], qs[FPT], qe[FPT], ql[FPT], qp[FPT];
  int qbs[FPT];
#pragma unroll
  for (int i = 0; i < FPT; i++) {
    int ki = k0 + i;
    int vb = 0, vs = 0, vj = 0;
    if (ki < K) {
      vb = b; vs = s; vj = j;
      j++;
      int lenb = shLen[b];
      int cs = lenb - s; if (cs > LLW) cs = LLW;
      if (j >= cs) { j = 0; s++; if (s >= lenb) { s = 0; b++; } }
    }
    qb[i] = (float)vb; qs[i] = (float)vs;
    qe[i] = (float)(vs + vj); ql[i] = (float)(vj + 1);
    qp[i] = pw[((size_t)vb * SS + vs) * LLW + vj];
    qbs[i] = (vb << 16) | vs;
  }
#pragma unroll
  for (int h = 0; h < FPT / 4; h++) {
    int o = 4 * h;
    *(float4*)(out + Nz + k0 + o)      = make_float4(qb[o], qb[o+1], qb[o+2], qb[o+3]);
    *(float4*)(out + 2 * Nz + k0 + o)  = make_float4(qs[o], qs[o+1], qs[o+2], qs[o+3]);
    *(float4*)(out + 3 * Nz + k0 + o)  = make_float4(qe[o], qe[o+1], qe[o+2], qe[o+3]);
    *(float4*)(out + 4 * Nz + k0 + o)  = make_float4(ql[o], ql[o+1], ql[o+2], ql[o+3]);
    *(float4*)(out + 25 * Nz + k0 + o) = make_float4(qp[o], qp[o+1], qp[o+2], qp[o+3]);
    *(int4*)(wsbs + k0 + o)            = make_int4(qbs[o], qbs[o+1], qbs[o+2], qbs[o+3]);
  }
}

// --------- K3: units region 5..24 — one contiguous 105 MB stream ------------
__global__ __launch_bounds__(TPB) void k_units(const int* __restrict__ seqs,
                                               const int* __restrict__ lens,
                                               const int* __restrict__ wsbs,
                                               float* __restrict__ out) {
  __shared__ int shC[TPB], shM[TPB], shLen[TPB];
  __shared__ int sBS[KPB3];
  __shared__ int sRows[MAXROWS * RSTRIDE];
  const int t = threadIdx.x;
  preamble(lens, shC, shM, shLen, t);
  const int K  = shC[BB - 1];
  const int ml = shM[0];
  const int blk_k0 = blockIdx.x * KPB3;
  const size_t Nz = (size_t)NN;

  // (b,s) table for this block's rows (coalesced int4)
  {
    const int4* src = (const int4*)(wsbs + blk_k0);
    ((int4*)sBS)[t] = src[t];            // 256 * int4 = 1024 ints
  }
  // stage seqs window
  int kq0 = blk_k0;            if (kq0 > K - 1) kq0 = K - 1;
  int kq1 = blk_k0 + KPB3 - 1; if (kq1 > K - 1) kq1 = K - 1;
  const int bf = batch_of(kq0, shC);
  int nrows = (blk_k0 < K) ? (batch_of(kq1, shC) - bf + 1) : 0;
  if (nrows > MAXROWS) nrows = MAXROWS;
  {
    const int4* src = (const int4*)(seqs + (size_t)bf * SS);
    for (int q = t; q < nrows * (SS / 4); q += TPB) {
      int lin = q << 2;
      int r = lin >> 9, p = lin & (SS - 1);
      *(int4*)(sRows + r * RSTRIDE + p) = src[q];
    }
  }
  __syncthreads();

  int ml1 = ml - 1;
  float4* udst = (float4*)(out + 5 * Nz + (size_t)blk_k0 * LLW);
  for (int c = 0; c < (KPB3 * (LLW / 4)) / TPB; c++) {   // 20 iterations
    int chunk = t + c * TPB;
    int krow  = chunk / 5;
    int e0    = (chunk - krow * 5) << 2;
    int bs    = sBS[krow];
    int b = bs >> 16, s = bs & 0xFFFF;
    int p0 = s + e0;     if (p0 > ml1) p0 = ml1;
    int p1 = s + e0 + 1; if (p1 > ml1) p1 = ml1;
    int p2 = s + e0 + 2; if (p2 > ml1) p2 = ml1;
    int p3 = s + e0 + 3; if (p3 > ml1) p3 = ml1;
    float4 v;
    int ridx = b - bf;
    if ((unsigned)ridx < (unsigned)nrows) {
      const int* rp = sRows + ridx * RSTRIDE;
      v.x = (float)rp[p0]; v.y = (float)rp[p1];
      v.z = (float)rp[p2]; v.w = (float)rp[p3];
    } else {
      const int* rp = seqs + (size_t)b * SS;
      v.x = (float)rp[p0]; v.y = (float)rp[p1];
      v.z = (float)rp[p2]; v.w = (float)rp[p3];
    }
    udst[chunk] = v;
  }
}

extern "C" void kernel_launch(void* const* d_in, const int* in_sizes, int n_in,
                              void* d_out, int out_size, void* d_ws, size_t ws_size,
                              hipStream_t stream) {
  const int*   seqs = (const int*)d_in[0];
  const int*   lens = (const int*)d_in[1];
  const float* pw   = (const float*)d_in[2];
  float* out = (float*)d_out;
  int*   wsbs = (int*)d_ws;              // N ints = 5.2 MB scratch

  k_cand <<<NN / (TPB * FPT), TPB, 0, stream>>>(lens, out);          // 640 blocks
  k_scal <<<NN / (TPB * FPT), TPB, 0, stream>>>(lens, pw, out, wsbs); // 640 blocks
  k_units<<<NN / KPB3,        TPB, 0, stream>>>(seqs, lens, wsbs, out); // 1280
}

// Round 11
// 171.047 us; speedup vs baseline: 1.0116x; 1.0116x over previous
//
#include <hip/hip_runtime.h>
#include <stdint.h>

#define TPB 256
#define BB  128
#define SS  512
#define LLW 20
#define NN  (BB * SS * LLW)   // 1,310,720
#define KPT 4                 // k's per thread
#define KPB (TPB * KPT)       // 1024 k's per block
#define MAXROWS 8             // staged seqs rows (proven bound: 6)
#define RSTRIDE 516           // LDS row stride (floats), 16B-aligned

// native vector type — __builtin_nontemporal_store rejects HIP_vector_type
typedef float nfv4 __attribute__((ext_vector_type(4)));

static __device__ __forceinline__ void ntst4(float* p, float a, float b,
                                             float c, float d) {
  nfv4 v = {a, b, c, d};
  __builtin_nontemporal_store(v, (nfv4*)p);
}

// lens -> LDS; inclusive prefix of per-batch viable counts
// (count(b) = L*len_b - L(L-1)/2, len>=L guaranteed) and max(lens).
static __device__ __forceinline__ void preamble(const int* __restrict__ lens,
                                                int* shC, int* shM, int* shLen,
                                                int t) {
  int len0 = (t < BB) ? lens[t] : 0;
  shLen[t] = len0;
  shC[t] = (t < BB) ? (LLW * len0 - (LLW * (LLW - 1)) / 2) : 0;
  shM[t] = len0;
  for (int off = 1; off < TPB; off <<= 1) {
    __syncthreads();
    int aC = shC[t]; int bC = (t >= off) ? shC[t - off] : 0;
    int aM = shM[t]; int bM = shM[t ^ off];
    __syncthreads();
    shC[t] = aC + bC;
    shM[t] = (aM > bM) ? aM : bM;
  }
  __syncthreads();
}

static __device__ __forceinline__ int batch_of(int k, const int* shC) {
  int lo = 0, hi = BB - 1;
  while (lo < hi) {
    int mid = (lo + hi) >> 1;
    if (shC[mid] > k) hi = mid; else lo = mid + 1;
  }
  return lo;
}

static __device__ __forceinline__ void invert(int k, const int* shC,
                                              const int* shLen, int K,
                                              int* pb, int* ps, int* pj) {
  int b = 0, s = 0, j = 0;
  if (k < K) {
    b = batch_of(k, shC);
    int base = (b == 0) ? 0 : shC[b - 1];
    int m    = k - base;
    int lenb = shLen[b];
    int full = LLW * (lenb - LLW + 1);
    if (m < full) {
      s = m / LLW;
      j = m - s * LLW;
    } else {                             // triangular tail; r = lenb - s
      int Cb = shC[b] - base;
      int tt = Cb - m;
      float rf = (sqrtf(8.0f * (float)tt + 1.0f) - 1.0f) * 0.5f;
      int r = (int)(rf + 0.5f);
      if (r * (r + 1) / 2 < tt) r++;
      if (r > 1 && r * (r - 1) / 2 >= tt) r--;
      s = lenb - r;
      j = r * (r + 1) / 2 - tt;
    }
  }
  *pb = b; *ps = s; *pj = j;
}

// d_out is FLOAT32. Return-order layout, offsets in units of NN:
//   0 viable | 1 batch | 2 starts | 3 ends | 4 lengths | 5..24 units
//   25 p_weights | 26 start_cand | 27 end_cand | 28 len_cand
__global__ __launch_bounds__(TPB) void span_full(
    const int* __restrict__ seqs,    // [B*S] int32
    const int* __restrict__ lens,    // [B] int32
    const float* __restrict__ pw,    // [B*S*L] f32
    float* __restrict__ out) {
  __shared__ int shC[TPB], shM[TPB], shLen[TPB];
  __shared__ int sBS[KPB];                    // packed (b<<16)|s per local k
  __shared__ float sRowsF[MAXROWS * RSTRIDE]; // staged seqs rows, pre-converted
  const int t = threadIdx.x;
  preamble(lens, shC, shM, shLen, t);
  const int K  = shC[BB - 1];
  const int ml = shM[0];

  const int gid    = blockIdx.x * TPB + t;
  const int k0     = gid * KPT;
  const int blk_k0 = blockIdx.x * KPB;
  const size_t Nz  = (size_t)NN;

  // ---- stage seqs window into LDS, converting int -> float at load time ----
  int kq0 = blk_k0;           if (kq0 > K - 1) kq0 = K - 1;
  int kq1 = blk_k0 + KPB - 1; if (kq1 > K - 1) kq1 = K - 1;
  const int bf = batch_of(kq0, shC);
  int nrows = (blk_k0 < K) ? (batch_of(kq1, shC) - bf + 1) : 0;
  if (nrows > MAXROWS) nrows = MAXROWS;       // defensive; bound proof says <= 6
  {
    const int4* src = (const int4*)(seqs + (size_t)bf * SS);
    for (int q = t; q < nrows * (SS / 4); q += TPB) {
      int lin = q << 2;
      int r = lin >> 9, p = lin & (SS - 1);
      int4 w = src[q];
      float4 v = make_float4((float)w.x, (float)w.y, (float)w.z, (float)w.w);
      *(float4*)(sRowsF + r * RSTRIDE + p) = v;
    }
  }

  // ---- phase 1a: candidate regions, incremental (row, jj) stepping ----
  {
    int row = k0 / LLW;                 // one const-div per thread
    int jj  = k0 - row * LLW;
    float qv[KPT], qsc[KPT], qec[KPT], qlc[KPT];
#pragma unroll
    for (int i = 0; i < KPT; i++) {
      int b = row >> 9;
      int s = row & (SS - 1);
      int e = s + jj;
      qv[i]  = (e < shLen[b]) ? 1.0f : 0.0f;
      qsc[i] = (float)s; qec[i] = (float)e; qlc[i] = (float)(jj + 1);
      if (++jj == LLW) { jj = 0; row++; }
    }
    ntst4(out + k0,           qv[0], qv[1], qv[2], qv[3]);
    ntst4(out + 26 * Nz + k0, qsc[0], qsc[1], qsc[2], qsc[3]);
    ntst4(out + 27 * Nz + k0, qec[0], qec[1], qec[2], qec[3]);
    ntst4(out + 28 * Nz + k0, qlc[0], qlc[1], qlc[2], qlc[3]);
  }
  // ---- phase 1b: compacted scalars, invert once + incremental stepping ----
  {
    int b, s, j;
    invert(k0, shC, shLen, K, &b, &s, &j);
    float qb[KPT], qs[KPT], qe[KPT], ql[KPT], qp[KPT];
#pragma unroll
    for (int i = 0; i < KPT; i++) {
      int ki = k0 + i;
      int vb = 0, vs = 0, vj = 0;
      if (ki < K) {
        vb = b; vs = s; vj = j;
        j++;
        int lenb = shLen[b];
        int cs = lenb - s; if (cs > LLW) cs = LLW;
        if (j >= cs) { j = 0; s++; if (s >= lenb) { s = 0; b++; } }
      }
      qb[i] = (float)vb; qs[i] = (float)vs;
      qe[i] = (float)(vs + vj); ql[i] = (float)(vj + 1);
      qp[i] = pw[((size_t)vb * SS + vs) * LLW + vj];
      sBS[t * KPT + i] = (vb << 16) | vs;
    }
    ntst4(out + Nz + k0,      qb[0], qb[1], qb[2], qb[3]);
    ntst4(out + 2 * Nz + k0,  qs[0], qs[1], qs[2], qs[3]);
    ntst4(out + 3 * Nz + k0,  qe[0], qe[1], qe[2], qe[3]);
    ntst4(out + 4 * Nz + k0,  ql[0], ql[1], ql[2], ql[3]);
    ntst4(out + 25 * Nz + k0, qp[0], qp[1], qp[2], qp[3]);
  }
  __syncthreads();
  // ---- phase 2: units region, pure LDS->reg->nt-store, incremental idx ----
  // Block span = 1024 rows x 5 float4 chunks = 5120; chunks never straddle rows.
  {
    int ml1 = ml - 1;
    float* ubase = out + 5 * Nz + (size_t)blk_k0 * LLW;
    int krow = t / 5;                   // chunk = t + c*256; 256 = 5*51 + 1
    int er   = t - krow * 5;
    int chunk = t;
#pragma unroll 4
    for (int c = 0; c < (KPB * (LLW / 4)) / TPB; c++) {   // 20 iterations
      int e0 = er << 2;
      int bs = sBS[krow];
      int b = bs >> 16, s = bs & 0xFFFF;
      int p0 = s + e0;     if (p0 > ml1) p0 = ml1;
      int p1 = s + e0 + 1; if (p1 > ml1) p1 = ml1;
      int p2 = s + e0 + 2; if (p2 > ml1) p2 = ml1;
      int p3 = s + e0 + 3; if (p3 > ml1) p3 = ml1;
      float x, y, z, w;
      int ridx = b - bf;
      if ((unsigned)ridx < (unsigned)nrows) {     // staged row (common case)
        const float* rp = sRowsF + ridx * RSTRIDE;
        x = rp[p0]; y = rp[p1]; z = rp[p2]; w = rp[p3];
      } else {                                    // pad / out-of-window row
        const int* rp = seqs + (size_t)b * SS;
        x = (float)rp[p0]; y = (float)rp[p1];
        z = (float)rp[p2]; w = (float)rp[p3];
      }
      ntst4(ubase + 4 * (size_t)chunk, x, y, z, w);
      chunk += TPB;
      krow += 51; er += 1;
      if (er >= 5) { er -= 5; krow++; }
    }
  }
}

extern "C" void kernel_launch(void* const* d_in, const int* in_sizes, int n_in,
                              void* d_out, int out_size, void* d_ws, size_t ws_size,
                              hipStream_t stream) {
  const int*   seqs = (const int*)d_in[0];    // lost_unit_id_seqs [128,512]
  const int*   lens = (const int*)d_in[1];    // lost_lengths [128]
  const float* pw   = (const float*)d_in[2];  // p_weights [128,512,20]
  float* out = (float*)d_out;

  span_full<<<NN / KPB, TPB, 0, stream>>>(seqs, lens, pw, out);  // 1280 blocks
}